// Round 8
// baseline (13.771 us; speedup 1.0000x reference)
//
#include <hip/hip_runtime.h>
#include <math.h>

#define BS 4
#define CH 256
#define XD 1024
#define N 128
#define NP 8128
#define TWO_PI_F 6.283185307179586f
#define PADU 132  // LDS row stride in u32 (half2 pairs): 528 B, 16B-aligned, 2-way bank alias only

typedef __fp16 h2v __attribute__((ext_vector_type(2)));

__device__ __forceinline__ h2v u2h(unsigned u) {
  union { unsigned u; h2v h; } x; x.u = u; return x.h;
}
__device__ __forceinline__ unsigned h2u(h2v h) {
  union { unsigned u; h2v h; } x; x.h = h; return x.u;
}

// ---------------------------------------------------------------------------
// K1: per-batch 16x16 pairdist tile (f16-packed LDS + v_dot2_f32_f16) plus
// the COMPLETE output write: out[e] = x[e] + (e in dims ? 0.5 : 1.0)*a[e].
// 1024 threads (16 waves = 4/SIMD) with a 4-way channel split per pair, so
// staging-gather and LDS latency are hidden across waves (R7 was 1 wave/SIMD).
//   vrS[b,i,j] = sqrt(sum_c (a_i-a_j)^2), mS = vrS*exp(-sqrt(sum_c (x_i-x_j)^2))
//   pmaxV/pmaxM[b*64+tile] = per-tile maxes (for the batch-level mask test)
// grid (8,8,4), ~42 KB LDS, __launch_bounds__(1024,4) -> VGPR<=128.
// ---------------------------------------------------------------------------
__global__ __launch_bounds__(1024, 4) void k1_pair_pass(
    const float* __restrict__ x, const float* __restrict__ a,
    const int* __restrict__ dims,
    float* __restrict__ vrS, float* __restrict__ mS,
    float* __restrict__ pmaxV, float* __restrict__ pmaxM,
    float* __restrict__ out) {
  int ti = blockIdx.x, tj = blockIdx.y, b = blockIdx.z;
  int t = threadIdx.x;
  __shared__ unsigned sXi[16][PADU], sXj[16][PADU], sAi[16][PADU], sAj[16][PADU];
  __shared__ float paccX[4][256], paccV[4][256];
  __shared__ unsigned inset[XD / 32];
  __shared__ float wred[16];

  if (t < XD / 32) inset[t] = 0u;
  __syncthreads();
  if (t < N) atomicOr(&inset[dims[t] >> 5], 1u << (dims[t] & 31));
  __syncthreads();

  // ---- full output write for this block's 4 rows (passthrough + fast path) ----
  {
    int B = (b << 6) + (tj << 3) + ti;  // 0..255
    int row = (B << 2) + (t >> 8);
    int e = t & 255;  // float4 index; elems 4e..4e+3
    const float4* x4 = (const float4*)(x + (size_t)row * XD);
    const float4* a4 = (const float4*)(a + (size_t)row * XD);
    float4* o4 = (float4*)(out + (size_t)row * XD);
    unsigned nib = (inset[e >> 3] >> ((e & 7) * 4)) & 0xFu;
    float4 xv = x4[e], av = a4[e];
    float4 o;
    o.x = fmaf((nib & 1u) ? 0.5f : 1.0f, av.x, xv.x);
    o.y = fmaf((nib & 2u) ? 0.5f : 1.0f, av.y, xv.y);
    o.z = fmaf((nib & 4u) ? 0.5f : 1.0f, av.z, xv.z);
    o.w = fmaf((nib & 8u) ? 0.5f : 1.0f, av.w, xv.w);
    o4[e] = o;
  }

  // ---- stage 4 slabs as packed f16 pairs: [16 dims][128 half2 ch-pairs] ----
  // slab s = t>>8: 0=Xi 1=Xj 2=Ai 3=Aj; within slab: 16 dims x 16 ch-groups.
  {
    int s = t >> 8, r = t & 255;
    int d16 = r & 15, grp = r >> 4;
    int c0 = grp * 16;
    int d = dims[((s & 1) ? tj : ti) * 16 + d16];
    const float* src = ((s >= 2) ? a : x) + (size_t)b * CH * XD;
    unsigned pk[8];
#pragma unroll
    for (int k = 0; k < 8; ++k) {
      float f0 = src[(size_t)(c0 + 2 * k) * XD + d];
      float f1 = src[(size_t)(c0 + 2 * k + 1) * XD + d];
      pk[k] = h2u(__builtin_amdgcn_cvt_pkrtz(f0, f1));
    }
    unsigned* dst = (s == 0) ? &sXi[d16][0]
                  : (s == 1) ? &sXj[d16][0]
                  : (s == 2) ? &sAi[d16][0]
                             : &sAj[d16][0];
    *(uint4*)&dst[grp * 8] = make_uint4(pk[0], pk[1], pk[2], pk[3]);
    *(uint4*)&dst[grp * 8 + 4] = make_uint4(pk[4], pk[5], pk[6], pk[7]);
  }
  __syncthreads();

  // ---- inner loop: pair p = t&255, channel chunk q = t>>8 (64 ch each) ----
  {
    int p = t & 255, q = t >> 8;
    int ii = p >> 4, jj = p & 15;
    int u0 = q * 32;  // u32 index base of this chunk
    float accx = 0.f, accv = 0.f;
#pragma unroll
    for (int cq = 0; cq < 8; ++cq) {
      uint4 xi = *(const uint4*)&sXi[ii][u0 + cq * 4];
      uint4 xj = *(const uint4*)&sXj[jj][u0 + cq * 4];
      uint4 ai = *(const uint4*)&sAi[ii][u0 + cq * 4];
      uint4 aj = *(const uint4*)&sAj[jj][u0 + cq * 4];
      h2v d0 = u2h(xi.x) - u2h(xj.x);
      accx = __builtin_amdgcn_fdot2(d0, d0, accx, false);
      h2v d1 = u2h(xi.y) - u2h(xj.y);
      accx = __builtin_amdgcn_fdot2(d1, d1, accx, false);
      h2v d2 = u2h(xi.z) - u2h(xj.z);
      accx = __builtin_amdgcn_fdot2(d2, d2, accx, false);
      h2v d3 = u2h(xi.w) - u2h(xj.w);
      accx = __builtin_amdgcn_fdot2(d3, d3, accx, false);
      h2v e0 = u2h(ai.x) - u2h(aj.x);
      accv = __builtin_amdgcn_fdot2(e0, e0, accv, false);
      h2v e1 = u2h(ai.y) - u2h(aj.y);
      accv = __builtin_amdgcn_fdot2(e1, e1, accv, false);
      h2v e2 = u2h(ai.z) - u2h(aj.z);
      accv = __builtin_amdgcn_fdot2(e2, e2, accv, false);
      h2v e3 = u2h(ai.w) - u2h(aj.w);
      accv = __builtin_amdgcn_fdot2(e3, e3, accv, false);
    }
    paccX[q][p] = accx;
    paccV[q][p] = accv;
  }
  __syncthreads();

  // ---- combine 4 chunks, write vr/m, per-tile max (threads 0..255) ----
  if (t < 256) {
    float accx = paccX[0][t] + paccX[1][t] + paccX[2][t] + paccX[3][t];
    float accv = paccV[0][t] + paccV[1][t] + paccV[2][t] + paccV[3][t];
    float vr = sqrtf(accv);
    float mv = vr * expf(-sqrtf(accx));
    int i = ti * 16 + (t >> 4), j = tj * 16 + (t & 15);
    vrS[((size_t)b * N + i) * N + j] = vr;
    mS[((size_t)b * N + i) * N + j] = mv;

    float wv = vr, wm = mv;
#pragma unroll
    for (int off = 32; off; off >>= 1) {
      wv = fmaxf(wv, __shfl_xor(wv, off));
      wm = fmaxf(wm, __shfl_xor(wm, off));
    }
    int wid = t >> 6;
    if ((t & 63) == 0) { wred[wid] = wv; wred[8 + wid] = wm; }
  }
  __syncthreads();
  if (t == 0) {
    int tile = (b << 6) + (ti << 3) + tj;
    pmaxV[tile] = fmaxf(fmaxf(wred[0], wred[1]), fmaxf(wred[2], wred[3]));
    pmaxM[tile] = fmaxf(fmaxf(wred[8], wred[9]), fmaxf(wred[10], wred[11]));
  }
}

// ---------------------------------------------------------------------------
// K2: conditional fixup. 32 blocks (8 c-groups x 4 batches) x 256 threads.
// Reduce the 64 partial maxes; if the collision mask is empty (always, for
// this data) exit immediately -- k1 already wrote the exact fast path.
// Otherwise recompute the masked update for this block's 32 channels.
// ---------------------------------------------------------------------------
__global__ __launch_bounds__(256) void k2_fixup(
    const float* __restrict__ x, const float* __restrict__ a,
    const float* __restrict__ ru, const int* __restrict__ dims,
    const float* __restrict__ vrS, const float* __restrict__ mS,
    const float* __restrict__ pmaxV, const float* __restrict__ pmaxM,
    float* __restrict__ out) {
  int cg = blockIdx.x, b = blockIdx.y;
  int t = threadIdx.x;
  __shared__ float mx2[2];
  __shared__ float xx[N], vv[N];
  __shared__ int dsh[N];

  if (t < 64) {
    float pv = pmaxV[(b << 6) + t];
    float pm = pmaxM[(b << 6) + t];
#pragma unroll
    for (int off = 32; off; off >>= 1) {
      pv = fmaxf(pv, __shfl_xor(pv, off));
      pm = fmaxf(pm, __shfl_xor(pm, off));
    }
    if (t == 0) { mx2[0] = pv; mx2[1] = pm; }
  }
  __syncthreads();
  float vrmax = mx2[0], mmax = mx2[1];
  float inv = vrmax > 0.f ? 1.f / vrmax : 0.f;
  if (!(mmax * inv > 0.5f)) return;  // mask empty: k1's fast path is exact

  // ---- slow path (general correctness; not taken for this input) ----
  if (t < N) dsh[t] = dims[t];
  for (int cc = 0; cc < 32; ++cc) {
    int c = (cg << 5) + cc;
    int bc = (b << 8) + c;
    __syncthreads();
    if (t < N) {
      int d = dsh[t];
      xx[t] = x[(size_t)bc * XD + d];
      vv[t] = a[(size_t)bc * XD + d];
    }
    __syncthreads();
    if (t < N) {
      int j = t;
      const float* mcol = mS + (size_t)b * N * N + j;
      const float* vcol = vrS + (size_t)b * N * N + j;
      const float* rub = ru + (size_t)bc * NP;
      float S = 0.f, sumV = 0.f, sumX = 0.f, R = 0.f;
      for (int i = 0; i < N; ++i) {
        float mv = mcol[(size_t)i * N];
        if (mv * inv > 0.5f) {
          S += 1.f;
          sumV += vv[i];
          sumX += xx[i];
          float vrv = vcol[(size_t)i * N];
          int p;
          float sgn;
          if (i < j) {
            p = i * N - ((i * (i + 1)) >> 1) + (j - i - 1);
            sgn = 1.f;
          } else {
            p = j * N - ((j * (j + 1)) >> 1) + (i - j - 1);
            sgn = -1.f;
          }
          R += sgn * TWO_PI_F * vrv * rub[p];
        }
      }
      float vj = vv[j];
      float v_new = vj + 0.5f * S * vj - 0.5f * sumV + R;
      float x_new = 0.5f * xx[j] + 0.5f * (xx[j] + sumX) / (S + 1.f) + 0.5f * v_new;
      out[(size_t)bc * XD + dsh[j]] = x_new;
    }
  }
}

extern "C" void kernel_launch(void* const* d_in, const int* in_sizes, int n_in,
                              void* d_out, int out_size, void* d_ws, size_t ws_size,
                              hipStream_t stream) {
  const float* x = (const float*)d_in[0];
  // d_in[1] = v : unused by the reference computation
  const float* a = (const float*)d_in[2];
  const float* ru = (const float*)d_in[3];
  const int* dims = (const int*)d_in[4];
  float* out = (float*)d_out;

  float* vrS = (float*)d_ws;               // BS*N*N f32 (256 KB)
  float* mS = vrS + (size_t)BS * N * N;    // BS*N*N f32 (256 KB)
  float* pmaxV = mS + (size_t)BS * N * N;  // BS*64 f32
  float* pmaxM = pmaxV + BS * 64;          // BS*64 f32

  k1_pair_pass<<<dim3(8, 8, BS), 1024, 0, stream>>>(x, a, dims, vrS, mS, pmaxV,
                                                    pmaxM, out);
  k2_fixup<<<dim3(8, BS), 256, 0, stream>>>(x, a, ru, dims, vrS, mS, pmaxV,
                                            pmaxM, out);
}